// Round 9
// baseline (244.850 us; speedup 1.0000x reference)
//
#include <hip/hip_runtime.h>
#include <hip/hip_fp16.h>
#include <math.h>

#define IN_DIM 256
#define HID 32
#define NSEG 100000

typedef _Float16 half8 __attribute__((ext_vector_type(8)));
typedef __fp16  fp16x2 __attribute__((ext_vector_type(2)));   // cvt_pkrtz return type
typedef float floatx4 __attribute__((ext_vector_type(4)));

// Fused q/k projection (f16 MFMA, fp32 accum) + per-row dot + exp + segment-sum.
// Register double-buffered, barrier-free main loop, NO LDS in steady state:
// each lane owns one x-row (16 float4 loads from one base, imm offsets);
// loop = cvt(raw->a) -> issue next subtile's loads into raw -> MFMA -> epilogue.
// Dependence-driven waits become counted (vmcnt(~17)): every wave keeps 16KB
// outstanding through its compute phase -> ~128KB in flight per CU, HBM never
// starves regardless of wave phase alignment.
__global__ __launch_bounds__(256, 2) void att_kernel(
    const float* __restrict__ x,
    const float* __restrict__ Wq, const float* __restrict__ bq,
    const float* __restrict__ Wk, const float* __restrict__ bk,
    const int* __restrict__ idx,
    float* __restrict__ e_out, float* __restrict__ segsum,
    int n, int nsub)
{
    __shared__ _Float16 BF[4 * 8 * 64 * 8];   // 32 KB, prologue only

    const int tid = threadIdx.x;
    const int w  = tid >> 6, l = tid & 63;
    const int lr = l & 15,  lg = l >> 4;

    // ---- prologue (block-wide, barriers ok): pack B fragments, copy to VGPRs
    {
        const int ks = tid >> 5, lg2 = (tid >> 3) & 3, j = tid & 7;
        const float4* wqr = (const float4*)(Wq + (size_t)tid * HID);
        const float4* wkr = (const float4*)(Wk + (size_t)tid * HID);
#pragma unroll
        for (int i = 0; i < 8; ++i) {
            float4 vq = wqr[i];
            float4 vk = wkr[i];
            float fq[4] = { vq.x, vq.y, vq.z, vq.w };
            float fk[4] = { vk.x, vk.y, vk.z, vk.w };
#pragma unroll
            for (int u2 = 0; u2 < 4; ++u2) {
                int c = i * 4 + u2, cg = c >> 4, cr = c & 15;
                BF[(((cg    ) * 8 + ks) * 64 + lg2 * 16 + cr) * 8 + j] = (_Float16)fq[u2];
                BF[(((cg + 2) * 8 + ks) * 64 + lg2 * 16 + cr) * 8 + j] = (_Float16)fk[u2];
            }
        }
    }
    __syncthreads();
    half8 b[4][8];   // 128 VGPR: b[cg][ks], cg = {q0,q1,k0,k1}
    {
        const _Float16* bfl = BF + (size_t)l * 8;
#pragma unroll
        for (int cg = 0; cg < 4; ++cg)
#pragma unroll
            for (int ks = 0; ks < 8; ++ks)
                b[cg][ks] = *(const half8*)(bfl + (cg * 8 + ks) * 512);
    }

    const float bq0 = bq[lr], bq1 = bq[lr + 16];
    const float bk0 = bk[lr], bk1 = bk[lr + 16];

    const int gw      = blockIdx.x * 4 + w;
    const int gstride = gridDim.x * 4;

    int s = gw;
    if (s >= nsub) return;

    // lane's loads: row = s*16 + lr, 8 contiguous floats at col lg*8 + ks*32
    // -> one base pointer, 16 imm-offset float4 loads (256B/lane, rows fully
    //    covered across the 4 lg groups -> every 64B line fully consumed)
    float4 raw[16];
    {
        int row = s * 16 + lr; if (row >= n) row = n - 1;
        const float* xp = x + (size_t)row * IN_DIM + lg * 8;
#pragma unroll
        for (int ks = 0; ks < 8; ++ks) {
            raw[2 * ks]     = *(const float4*)(xp + ks * 32);
            raw[2 * ks + 1] = *(const float4*)(xp + ks * 32 + 4);
        }
    }

    while (true) {
        const int snext = s + gstride;

        // convert current raw -> fp16 fragments (waits only on own 16 loads;
        // epilogue store/atomic from last iter keep flying: counted vmcnt)
        half8 a[8];
#pragma unroll
        for (int ks = 0; ks < 8; ++ks) {
            float4 v0 = raw[2 * ks], v1 = raw[2 * ks + 1];
            union { half8 h8; fp16x2 h2[4]; } u;
            u.h2[0] = __builtin_amdgcn_cvt_pkrtz(v0.x, v0.y);
            u.h2[1] = __builtin_amdgcn_cvt_pkrtz(v0.z, v0.w);
            u.h2[2] = __builtin_amdgcn_cvt_pkrtz(v1.x, v1.y);
            u.h2[3] = __builtin_amdgcn_cvt_pkrtz(v1.z, v1.w);
            a[ks] = u.h8;
        }

        // issue next subtile's 16 loads NOW -> in flight through MFMA+epilogue
        if (snext < nsub) {
            int row = snext * 16 + lr; if (row >= n) row = n - 1;
            const float* xp = x + (size_t)row * IN_DIM + lg * 8;
#pragma unroll
            for (int ks = 0; ks < 8; ++ks) {
                raw[2 * ks]     = *(const float4*)(xp + ks * 32);
                raw[2 * ks + 1] = *(const float4*)(xp + ks * 32 + 4);
            }
        }
        __builtin_amdgcn_sched_barrier(0);   // pin load issue before MFMA block

        floatx4 acc0 = {0.f,0.f,0.f,0.f}, acc1 = {0.f,0.f,0.f,0.f};
        floatx4 acc2 = {0.f,0.f,0.f,0.f}, acc3 = {0.f,0.f,0.f,0.f};
#pragma unroll
        for (int ks = 0; ks < 8; ++ks) {
            acc0 = __builtin_amdgcn_mfma_f32_16x16x32_f16(a[ks], b[0][ks], acc0, 0, 0, 0);
            acc1 = __builtin_amdgcn_mfma_f32_16x16x32_f16(a[ks], b[1][ks], acc1, 0, 0, 0);
            acc2 = __builtin_amdgcn_mfma_f32_16x16x32_f16(a[ks], b[2][ks], acc2, 0, 0, 0);
            acc3 = __builtin_amdgcn_mfma_f32_16x16x32_f16(a[ks], b[3][ks], acc3, 0, 0, 0);
        }

        // att = sum_h (qv+bq)*(kv+bk); reduce over the 16 col-lanes
        float p[4];
#pragma unroll
        for (int i2 = 0; i2 < 4; ++i2) {
            p[i2] = (acc0[i2] + bq0) * (acc2[i2] + bk0)
                  + (acc1[i2] + bq1) * (acc3[i2] + bk1);
            p[i2] += __shfl_xor(p[i2], 1);
            p[i2] += __shfl_xor(p[i2], 2);
            p[i2] += __shfl_xor(p[i2], 4);
            p[i2] += __shfl_xor(p[i2], 8);
        }

        // epilogue: fire-and-forget (never waited to 0 inside the loop)
        if (lr < 4) {   // 16 lanes each store one row: r = s*16 + lg*4 + lr
            float pv = (lr & 1) ? ((lr & 2) ? p[3] : p[1])
                                : ((lr & 2) ? p[2] : p[0]);
            int r = s * 16 + lg * 4 + lr;
            if (r < n) {
                float e = __expf(pv);   // no max-subtract: |att| small enough for f32
                e_out[r] = e;
                atomicAdd(&segsum[idx[r]], e);
            }
        }

        if (snext >= nsub) break;
        s = snext;
    }
}

// out = e / segsum[idx], float4-vectorized
__global__ __launch_bounds__(256) void norm_kernel(
    const int* __restrict__ idx, const float* __restrict__ segsum,
    float* __restrict__ out, int n)
{
    int i = blockIdx.x * blockDim.x + threadIdx.x;
    int stride = gridDim.x * blockDim.x;
    int n4 = n >> 2;
    for (; i < n4; i += stride) {
        float4 e = ((const float4*)out)[i];
        int4  s4 = ((const int4*)idx)[i];
        float4 r;
        r.x = e.x / segsum[s4.x];
        r.y = e.y / segsum[s4.y];
        r.z = e.z / segsum[s4.z];
        r.w = e.w / segsum[s4.w];
        ((float4*)out)[i] = r;
    }
    if (blockIdx.x == 0 && threadIdx.x < (n & 3)) {
        int j = (n & ~3) + threadIdx.x;
        out[j] = out[j] / segsum[idx[j]];
    }
}

extern "C" void kernel_launch(void* const* d_in, const int* in_sizes, int n_in,
                              void* d_out, int out_size, void* d_ws, size_t ws_size,
                              hipStream_t stream)
{
    const float* x   = (const float*)d_in[0];
    const float* Wq  = (const float*)d_in[1];
    const float* bq  = (const float*)d_in[2];
    const float* Wk  = (const float*)d_in[3];
    const float* bk  = (const float*)d_in[4];
    const int*   idx = (const int*)d_in[5];
    const int n = in_sizes[5];

    float* segsum = (float*)d_ws;  // NSEG floats

    (void)hipMemsetAsync(segsum, 0, (size_t)NSEG * 4, stream);

    const int nsub = (n + 15) >> 4;           // 16-row subtiles
    int grid1 = 512;                          // 2 blocks/CU, 2048 waves
    if (grid1 * 4 > nsub) grid1 = (nsub + 3) / 4;
    att_kernel<<<grid1, 256, 0, stream>>>(x, Wq, bq, Wk, bk, idx,
                                          (float*)d_out, segsum, n, nsub);

    int n4 = n >> 2;
    int grid2 = (n4 + 255) / 256;
    if (grid2 > 1024) grid2 = 1024;
    if (grid2 < 1) grid2 = 1;
    norm_kernel<<<grid2, 256, 0, stream>>>(idx, segsum, (float*)d_out, n);
}

// Round 10
// 239.094 us; speedup vs baseline: 1.0241x; 1.0241x over previous
//
#include <hip/hip_runtime.h>
#include <hip/hip_fp16.h>
#include <math.h>

#define IN_DIM 256
#define HID 32
#define NSEG 100000
#define ROWB 1024     // bytes per x-row (256 f32)
#define WBUF 16384    // one X buffer: 16 rows x 1KB

typedef _Float16 half8 __attribute__((ext_vector_type(8)));
typedef __fp16  fp16x2 __attribute__((ext_vector_type(2)));   // cvt_pkrtz return type
typedef float floatx4 __attribute__((ext_vector_type(4)));

// async global->LDS, 16B per lane, dest = wave-uniform base + lane*16 (m104)
__device__ __forceinline__ void gload_lds16(const float* g, char* l) {
    __builtin_amdgcn_global_load_lds(
        (const __attribute__((address_space(1))) void*)g,
        (__attribute__((address_space(3))) void*)l,
        16, 0, 0);
}

// Fused q/k projection (f16 MFMA, fp32 accum) + per-row dot + exp + segment-sum.
// KEY FIX vs R6-R9 (the vmcnt FIFO drain trap): vmcnt is FIFO by issue order,
// so the epilogue's idx[r] load — issued AFTER the stage — forced an effective
// vmcnt(0) drain of the 16 stage loads on every iteration (compute always ran
// with zero loads in flight). Now: idx is loaded BEFORE the stage (consuming it
// costs vmcnt(16), stage keeps flying), and each wave double-buffers its
// private 16KB LDS tile, so its 16 loads stay outstanding through the entire
// compute phase. Barrier-free main loop; 2-wave blocks; 64KB dynamic LDS.
__global__ __launch_bounds__(128) void att_kernel(
    const float* __restrict__ x,
    const float* __restrict__ Wq, const float* __restrict__ bq,
    const float* __restrict__ Wk, const float* __restrict__ bk,
    const int* __restrict__ idx,
    float* __restrict__ e_out, float* __restrict__ segsum,
    int n, int nsub)
{
    extern __shared__ char smem[];   // 64KB: BF (32KB, prologue) overlapped with 2 waves x 2x16KB

    const int tid = threadIdx.x;
    const int w  = tid >> 6, l = tid & 63;   // w in {0,1}
    const int lr = l & 15,  lg = l >> 4;

    // ---- prologue (block-wide, barriers ok): pack B fragments, copy to VGPRs
    {
        _Float16* BF = (_Float16*)smem;
#pragma unroll
        for (int rr = 0; rr < 2; ++rr) {
            const int k = tid + rr * 128;             // W row (0..255)
            const int ks = k >> 5, lg2 = (k >> 3) & 3, j = k & 7;
            const float4* wqr = (const float4*)(Wq + (size_t)k * HID);
            const float4* wkr = (const float4*)(Wk + (size_t)k * HID);
#pragma unroll
            for (int i = 0; i < 8; ++i) {
                float4 vq = wqr[i];
                float4 vk = wkr[i];
                float fq[4] = { vq.x, vq.y, vq.z, vq.w };
                float fk[4] = { vk.x, vk.y, vk.z, vk.w };
#pragma unroll
                for (int u2 = 0; u2 < 4; ++u2) {
                    int c = i * 4 + u2, cg = c >> 4, cr = c & 15;
                    BF[(((cg    ) * 8 + ks) * 64 + lg2 * 16 + cr) * 8 + j] = (_Float16)fq[u2];
                    BF[(((cg + 2) * 8 + ks) * 64 + lg2 * 16 + cr) * 8 + j] = (_Float16)fk[u2];
                }
            }
        }
    }
    __syncthreads();
    half8 b[4][8];   // 128 VGPR: b[cg][ks], cg = {q0,q1,k0,k1}
    {
        const _Float16* bfl = (const _Float16*)smem + (size_t)l * 8;
#pragma unroll
        for (int cg = 0; cg < 4; ++cg)
#pragma unroll
            for (int ks = 0; ks < 8; ++ks)
                b[cg][ks] = *(const half8*)(bfl + (cg * 8 + ks) * 512);
    }
    __syncthreads();   // BF consumed; smem free for per-wave X buffers

    const float bq0 = bq[lr], bq1 = bq[lr + 16];
    const float bk0 = bk[lr], bk1 = bk[lr + 16];

    char* const Xw = smem + w * (2 * WBUF);   // this wave's two buffers
    const int sw = lr & 7;

    // stage subtile s into buffer: LDS linear, source pre-swizzled
    //   LDS[r][chunk c] = G[row][c ^ (r&7)]  (16B chunks)
    auto stage = [&](int s, int bufsel) {
        char* buf = Xw + bufsel * WBUF;
#pragma unroll
        for (int r = 0; r < 16; ++r) {
            int grow = s * 16 + r;
            if (grow >= n) grow = n - 1;
            const float* src = x + (size_t)grow * IN_DIM + ((l ^ (r & 7)) << 2);
            gload_lds16(src, buf + r * ROWB);
        }
    };

    const int gw      = blockIdx.x * 2 + w;
    const int gstride = gridDim.x * 2;

    int s = gw;
    if (s >= nsub) return;   // after both barriers: safe

    int cur = 0;
    stage(s, cur);

    while (true) {
        const int snext = s + gstride;

        // buf[cur]'s 16 loads complete (issued a full iteration ago in steady
        // state; epilogue store/atomic from last iter are also old by now)
        asm volatile("s_waitcnt vmcnt(0)" ::: "memory");
        __builtin_amdgcn_sched_barrier(0);

        // idx for THIS subtile's epilogue: issued BEFORE the stage, so the
        // epilogue's use waits at vmcnt(16) and never drains the stage.
        const int r_ep = s * 16 + lg * 4 + lr;   // row handled by lanes lr<4
        int my_seg = 0;
        if (lr < 4 && r_ep < n) my_seg = idx[r_ep];
        __builtin_amdgcn_sched_barrier(0);       // pin idx load before stage

        if (snext < nsub) stage(snext, cur ^ 1); // 16 loads fly through compute
        __builtin_amdgcn_sched_barrier(0);

        // ---- compute from buf[cur]: lane's A-row = subtile row lr
        const char* Xr = Xw + cur * WBUF + lr * ROWB;
        floatx4 acc0 = {0.f,0.f,0.f,0.f}, acc1 = {0.f,0.f,0.f,0.f};
        floatx4 acc2 = {0.f,0.f,0.f,0.f}, acc3 = {0.f,0.f,0.f,0.f};
#pragma unroll
        for (int ks = 0; ks < 8; ++ks) {
            float4 v0 = *(const float4*)(Xr + ks * 128 + (((lg * 2 + 0) ^ sw) << 4));
            float4 v1 = *(const float4*)(Xr + ks * 128 + (((lg * 2 + 1) ^ sw) << 4));
            union { half8 h8; fp16x2 h2[4]; } u;
            u.h2[0] = __builtin_amdgcn_cvt_pkrtz(v0.x, v0.y);
            u.h2[1] = __builtin_amdgcn_cvt_pkrtz(v0.z, v0.w);
            u.h2[2] = __builtin_amdgcn_cvt_pkrtz(v1.x, v1.y);
            u.h2[3] = __builtin_amdgcn_cvt_pkrtz(v1.z, v1.w);
            acc0 = __builtin_amdgcn_mfma_f32_16x16x32_f16(u.h8, b[0][ks], acc0, 0, 0, 0);
            acc1 = __builtin_amdgcn_mfma_f32_16x16x32_f16(u.h8, b[1][ks], acc1, 0, 0, 0);
            acc2 = __builtin_amdgcn_mfma_f32_16x16x32_f16(u.h8, b[2][ks], acc2, 0, 0, 0);
            acc3 = __builtin_amdgcn_mfma_f32_16x16x32_f16(u.h8, b[3][ks], acc3, 0, 0, 0);
        }

        // att = sum_h (qv+bq)*(kv+bk); reduce over the 16 col-lanes
        float p[4];
#pragma unroll
        for (int i2 = 0; i2 < 4; ++i2) {
            p[i2] = (acc0[i2] + bq0) * (acc2[i2] + bk0)
                  + (acc1[i2] + bq1) * (acc3[i2] + bk1);
            p[i2] += __shfl_xor(p[i2], 1);
            p[i2] += __shfl_xor(p[i2], 2);
            p[i2] += __shfl_xor(p[i2], 4);
            p[i2] += __shfl_xor(p[i2], 8);
        }

        // epilogue: uses pre-loaded my_seg (vmcnt(16) — stage keeps flying);
        // store + atomic are fire-and-forget, drained by next iter's vmcnt(0)
        if (lr < 4 && r_ep < n) {
            float pv = (lr & 1) ? ((lr & 2) ? p[3] : p[1])
                                : ((lr & 2) ? p[2] : p[0]);
            float e = __expf(pv);   // no max-subtract: |att| small enough for f32
            e_out[r_ep] = e;
            atomicAdd(&segsum[my_seg], e);
        }

        // own ds_reads (incl. shfl ds-ops) retired -> buf[cur] safe to restage
        asm volatile("s_waitcnt lgkmcnt(0)" ::: "memory");
        __builtin_amdgcn_sched_barrier(0);

        if (snext >= nsub) break;
        s = snext;
        cur ^= 1;
    }
}

// out = e / segsum[idx], float4-vectorized
__global__ __launch_bounds__(256) void norm_kernel(
    const int* __restrict__ idx, const float* __restrict__ segsum,
    float* __restrict__ out, int n)
{
    int i = blockIdx.x * blockDim.x + threadIdx.x;
    int stride = gridDim.x * blockDim.x;
    int n4 = n >> 2;
    for (; i < n4; i += stride) {
        float4 e = ((const float4*)out)[i];
        int4  s4 = ((const int4*)idx)[i];
        float4 r;
        r.x = e.x / segsum[s4.x];
        r.y = e.y / segsum[s4.y];
        r.z = e.z / segsum[s4.z];
        r.w = e.w / segsum[s4.w];
        ((float4*)out)[i] = r;
    }
    if (blockIdx.x == 0 && threadIdx.x < (n & 3)) {
        int j = (n & ~3) + threadIdx.x;
        out[j] = out[j] / segsum[idx[j]];
    }
}

extern "C" void kernel_launch(void* const* d_in, const int* in_sizes, int n_in,
                              void* d_out, int out_size, void* d_ws, size_t ws_size,
                              hipStream_t stream)
{
    const float* x   = (const float*)d_in[0];
    const float* Wq  = (const float*)d_in[1];
    const float* bq  = (const float*)d_in[2];
    const float* Wk  = (const float*)d_in[3];
    const float* bk  = (const float*)d_in[4];
    const int*   idx = (const int*)d_in[5];
    const int n = in_sizes[5];

    float* segsum = (float*)d_ws;  // NSEG floats

    (void)hipMemsetAsync(segsum, 0, (size_t)NSEG * 4, stream);

    const int nsub = (n + 15) >> 4;           // 16-row subtiles
    int grid1 = 512;                          // 2 blocks/CU (64KB LDS), 1024 wave-streams
    if (grid1 * 2 > nsub) grid1 = (nsub + 1) / 2;
    att_kernel<<<grid1, 128, 65536, stream>>>(x, Wq, bq, Wk, bk, idx,
                                              (float*)d_out, segsum, n, nsub);

    int n4 = n >> 2;
    int grid2 = (n4 + 255) / 256;
    if (grid2 > 1024) grid2 = 1024;
    if (grid2 < 1) grid2 = 1;
    norm_kernel<<<grid2, 256, 0, stream>>>(idx, segsum, (float*)d_out, n);
}

// Round 11
// 218.640 us; speedup vs baseline: 1.1199x; 1.0935x over previous
//
#include <hip/hip_runtime.h>
#include <hip/hip_fp16.h>
#include <math.h>

#define IN_DIM 256
#define HID 32
#define NSEG 100000
#define ROWB 1024     // bytes per x-row (256 f32)
#define WBUF 16384    // one X buffer: 16 rows x 1KB

typedef _Float16 half8 __attribute__((ext_vector_type(8)));
typedef __fp16  fp16x2 __attribute__((ext_vector_type(2)));   // cvt_pkrtz return type
typedef float floatx4 __attribute__((ext_vector_type(4)));

// async global->LDS, 16B per lane, dest = wave-uniform base + lane*16 (m104)
__device__ __forceinline__ void gload_lds16(const float* g, char* l) {
    __builtin_amdgcn_global_load_lds(
        (const __attribute__((address_space(1))) void*)g,
        (__attribute__((address_space(3))) void*)l,
        16, 0, 0);
}

// Fused q/k projection (f16 MFMA, fp32 accum) + per-row dot + exp + segment-sum.
// R11 = R10 dbuf + COUNTED drain (T4): per iteration the wave issues
//   stage(s+g) [16 gload_lds] ; idx(s+g) [1 load]   (order pinned)
// computes buf[cur], fires e_out store + atomicAdd, then waits vmcnt(3):
// the 16 stage loads are retired (vmcnt FIFO is in-order, m135) while
// idx+store+atomic continue flying across the iteration boundary. The wave
// never sits with zero loads issued -> ~16KB outstanding per wave at all
// times; 4 waves/CU x 16KB covers the latency-BW product with margin.
__global__ __launch_bounds__(128) void att_kernel(
    const float* __restrict__ x,
    const float* __restrict__ Wq, const float* __restrict__ bq,
    const float* __restrict__ Wk, const float* __restrict__ bk,
    const int* __restrict__ idx,
    float* __restrict__ e_out, float* __restrict__ segsum,
    int n, int nsub)
{
    extern __shared__ char smem[];   // 64KB: BF (32KB, prologue) overlapped with 2 waves x 2x16KB

    const int tid = threadIdx.x;
    const int w  = tid >> 6, l = tid & 63;   // w in {0,1}
    const int lr = l & 15,  lg = l >> 4;

    // ---- prologue (block-wide, barriers ok): pack B fragments, copy to VGPRs
    {
        _Float16* BF = (_Float16*)smem;
#pragma unroll
        for (int rr = 0; rr < 2; ++rr) {
            const int k = tid + rr * 128;             // W row (0..255)
            const int ks = k >> 5, lg2 = (k >> 3) & 3, j = k & 7;
            const float4* wqr = (const float4*)(Wq + (size_t)k * HID);
            const float4* wkr = (const float4*)(Wk + (size_t)k * HID);
#pragma unroll
            for (int i = 0; i < 8; ++i) {
                float4 vq = wqr[i];
                float4 vk = wkr[i];
                float fq[4] = { vq.x, vq.y, vq.z, vq.w };
                float fk[4] = { vk.x, vk.y, vk.z, vk.w };
#pragma unroll
                for (int u2 = 0; u2 < 4; ++u2) {
                    int c = i * 4 + u2, cg = c >> 4, cr = c & 15;
                    BF[(((cg    ) * 8 + ks) * 64 + lg2 * 16 + cr) * 8 + j] = (_Float16)fq[u2];
                    BF[(((cg + 2) * 8 + ks) * 64 + lg2 * 16 + cr) * 8 + j] = (_Float16)fk[u2];
                }
            }
        }
    }
    __syncthreads();
    half8 b[4][8];   // 128 VGPR: b[cg][ks], cg = {q0,q1,k0,k1}
    {
        const _Float16* bfl = (const _Float16*)smem + (size_t)l * 8;
#pragma unroll
        for (int cg = 0; cg < 4; ++cg)
#pragma unroll
            for (int ks = 0; ks < 8; ++ks)
                b[cg][ks] = *(const half8*)(bfl + (cg * 8 + ks) * 512);
    }
    __syncthreads();   // BF consumed; smem free for per-wave X buffers

    const float bq0 = bq[lr], bq1 = bq[lr + 16];
    const float bk0 = bk[lr], bk1 = bk[lr + 16];

    char* const Xw = smem + w * (2 * WBUF);   // this wave's two buffers
    const int sw = lr & 7;

    // stage subtile s into buffer: LDS linear, source pre-swizzled
    //   LDS[r][chunk c] = G[row][c ^ (r&7)]  (16B chunks)
    auto stage = [&](int s, int bufsel) {
        char* buf = Xw + bufsel * WBUF;
#pragma unroll
        for (int r = 0; r < 16; ++r) {
            int grow = s * 16 + r;
            if (grow >= n) grow = n - 1;
            const float* src = x + (size_t)grow * IN_DIM + ((l ^ (r & 7)) << 2);
            gload_lds16(src, buf + r * ROWB);
        }
    };

    const int gw      = blockIdx.x * 2 + w;
    const int gstride = gridDim.x * 2;

    int s = gw;
    if (s >= nsub) return;   // after both barriers: safe

    int cur = 0;
    stage(s, 0);
    // idx for subtile s's epilogue (unconditional, clamped: deterministic FIFO count)
    int r_ep = s * 16 + lg * 4 + lr;
    int my_seg = idx[r_ep < n ? r_ep : (n - 1)];
    asm volatile("s_waitcnt vmcnt(0)" ::: "memory");   // prologue drain (once)
    __builtin_amdgcn_sched_barrier(0);

    while (true) {
        const int snext = s + gstride;

        // ---- issue next subtile's stream FIRST: 16 stage loads, then idx
        int r_next = 0, seg_next = 0;
        if (snext < nsub) {
            stage(snext, cur ^ 1);
            __builtin_amdgcn_sched_barrier(0);         // pin: stage BEFORE idx
            r_next = snext * 16 + lg * 4 + lr;
            seg_next = idx[r_next < n ? r_next : (n - 1)];
        }
        __builtin_amdgcn_sched_barrier(0);

        // ---- compute from buf[cur] (its loads were drained last iteration)
        const char* Xr = Xw + cur * WBUF + lr * ROWB;
        floatx4 acc0 = {0.f,0.f,0.f,0.f}, acc1 = {0.f,0.f,0.f,0.f};
        floatx4 acc2 = {0.f,0.f,0.f,0.f}, acc3 = {0.f,0.f,0.f,0.f};
#pragma unroll
        for (int ks = 0; ks < 8; ++ks) {
            float4 v0 = *(const float4*)(Xr + ks * 128 + (((lg * 2 + 0) ^ sw) << 4));
            float4 v1 = *(const float4*)(Xr + ks * 128 + (((lg * 2 + 1) ^ sw) << 4));
            union { half8 h8; fp16x2 h2[4]; } u;
            u.h2[0] = __builtin_amdgcn_cvt_pkrtz(v0.x, v0.y);
            u.h2[1] = __builtin_amdgcn_cvt_pkrtz(v0.z, v0.w);
            u.h2[2] = __builtin_amdgcn_cvt_pkrtz(v1.x, v1.y);
            u.h2[3] = __builtin_amdgcn_cvt_pkrtz(v1.z, v1.w);
            acc0 = __builtin_amdgcn_mfma_f32_16x16x32_f16(u.h8, b[0][ks], acc0, 0, 0, 0);
            acc1 = __builtin_amdgcn_mfma_f32_16x16x32_f16(u.h8, b[1][ks], acc1, 0, 0, 0);
            acc2 = __builtin_amdgcn_mfma_f32_16x16x32_f16(u.h8, b[2][ks], acc2, 0, 0, 0);
            acc3 = __builtin_amdgcn_mfma_f32_16x16x32_f16(u.h8, b[3][ks], acc3, 0, 0, 0);
        }

        // att = sum_h (qv+bq)*(kv+bk); reduce over the 16 col-lanes
        float p[4];
#pragma unroll
        for (int i2 = 0; i2 < 4; ++i2) {
            p[i2] = (acc0[i2] + bq0) * (acc2[i2] + bk0)
                  + (acc1[i2] + bq1) * (acc3[i2] + bk1);
            p[i2] += __shfl_xor(p[i2], 1);
            p[i2] += __shfl_xor(p[i2], 2);
            p[i2] += __shfl_xor(p[i2], 4);
            p[i2] += __shfl_xor(p[i2], 8);
        }

        // epilogue: store + atomic fire-and-forget (they ride across the
        // iteration boundary — the counted drain below never waits for them)
        if (lr < 4 && r_ep < n) {
            float pv = (lr & 1) ? ((lr & 2) ? p[3] : p[1])
                                : ((lr & 2) ? p[2] : p[0]);
            float e = __expf(pv);   // no max-subtract: |att| small enough for f32
            e_out[r_ep] = e;
            atomicAdd(&segsum[my_seg], e);
        }

        if (snext >= nsub) break;

        // own ds_reads retired -> buf[cur] safe to restage next iteration
        asm volatile("s_waitcnt lgkmcnt(0)" ::: "memory");
        // COUNTED drain: outstanding FIFO = [stage(snext) x16, idx, store, atomic];
        // vmcnt(3) retires exactly the 16 stage loads (in-order retirement, m135)
        asm volatile("s_waitcnt vmcnt(3)" ::: "memory");
        __builtin_amdgcn_sched_barrier(0);

        s = snext;
        r_ep = r_next;
        my_seg = seg_next;
        cur ^= 1;
    }
}

// out = e / segsum[idx], float4-vectorized
__global__ __launch_bounds__(256) void norm_kernel(
    const int* __restrict__ idx, const float* __restrict__ segsum,
    float* __restrict__ out, int n)
{
    int i = blockIdx.x * blockDim.x + threadIdx.x;
    int stride = gridDim.x * blockDim.x;
    int n4 = n >> 2;
    for (; i < n4; i += stride) {
        float4 e = ((const float4*)out)[i];
        int4  s4 = ((const int4*)idx)[i];
        float4 r;
        r.x = e.x / segsum[s4.x];
        r.y = e.y / segsum[s4.y];
        r.z = e.z / segsum[s4.z];
        r.w = e.w / segsum[s4.w];
        ((float4*)out)[i] = r;
    }
    if (blockIdx.x == 0 && threadIdx.x < (n & 3)) {
        int j = (n & ~3) + threadIdx.x;
        out[j] = out[j] / segsum[idx[j]];
    }
}

extern "C" void kernel_launch(void* const* d_in, const int* in_sizes, int n_in,
                              void* d_out, int out_size, void* d_ws, size_t ws_size,
                              hipStream_t stream)
{
    const float* x   = (const float*)d_in[0];
    const float* Wq  = (const float*)d_in[1];
    const float* bq  = (const float*)d_in[2];
    const float* Wk  = (const float*)d_in[3];
    const float* bk  = (const float*)d_in[4];
    const int*   idx = (const int*)d_in[5];
    const int n = in_sizes[5];

    float* segsum = (float*)d_ws;  // NSEG floats

    (void)hipMemsetAsync(segsum, 0, (size_t)NSEG * 4, stream);

    const int nsub = (n + 15) >> 4;           // 16-row subtiles
    int grid1 = 512;                          // 2 blocks/CU (64KB LDS), 1024 wave-streams
    if (grid1 * 2 > nsub) grid1 = (nsub + 1) / 2;
    att_kernel<<<grid1, 128, 65536, stream>>>(x, Wq, bq, Wk, bk, idx,
                                              (float*)d_out, segsum, n, nsub);

    int n4 = n >> 2;
    int grid2 = (n4 + 255) / 256;
    if (grid2 > 1024) grid2 = 1024;
    if (grid2 < 1) grid2 = 1;
    norm_kernel<<<grid2, 256, 0, stream>>>(idx, segsum, (float*)d_out, n);
}